// Round 18
// baseline (109.706 us; speedup 1.0000x reference)
//
#include <hip/hip_runtime.h>
#include <cstdint>

typedef unsigned short u16;
typedef __attribute__((ext_vector_type(4))) float f32x4;
typedef __attribute__((ext_vector_type(8))) short bf16x8;

// ---------- helpers ----------
__device__ __forceinline__ u16 f2bf(float f) {
  uint32_t u = __builtin_bit_cast(uint32_t, f);
  u += 0x7FFFu + ((u >> 16) & 1u);   // RNE
  return (u16)(u >> 16);
}

__device__ __forceinline__ void gld16(const void* g, void* l) {
  __builtin_amdgcn_global_load_lds((const __attribute__((address_space(1))) void*)g,
                                   (__attribute__((address_space(3))) void*)l,
                                   16, 0, 0);
}

// ---------- all f32->bf16 casts in one launch ----------
__global__ __launch_bounds__(256) void cast_all(const float* __restrict__ xq, const float* __restrict__ xk,
                                                const float* __restrict__ xv, const float* __restrict__ Wq,
                                                const float* __restrict__ Wk, const float* __restrict__ Wv,
                                                const float* __restrict__ Wp,
                                                u16* __restrict__ oq, u16* __restrict__ ok, u16* __restrict__ ov,
                                                u16* __restrict__ owq, u16* __restrict__ owk,
                                                u16* __restrict__ owv, u16* __restrict__ owp) {
  int bid = blockIdx.x;
  const float* src; u16* dst; size_t i;
  if (bid < 12288) {              // 3 x tensors, 4096 blocks each
    const int p = bid >> 12, ib = bid & 4095;
    src = (p == 0) ? xq : ((p == 1) ? xk : xv);
    dst = (p == 0) ? oq : ((p == 1) ? ok : ov);
    i = (size_t)ib * 256 + threadIdx.x;
  } else {                        // 4 weights, 1024 blocks each
    bid -= 12288;
    const int p = bid >> 10, ib = bid & 1023;
    src = (p == 0) ? Wq : ((p == 1) ? Wk : ((p == 2) ? Wv : Wp));
    dst = (p == 0) ? owq : ((p == 1) ? owk : ((p == 2) ? owv : owp));
    i = (size_t)ib * 256 + threadIdx.x;
  }
  float4 v = *(const float4*)(src + i * 4);
  uint2 pk;
  pk.x = (uint32_t)f2bf(v.x) | ((uint32_t)f2bf(v.y) << 16);
  pk.y = (uint32_t)f2bf(v.z) | ((uint32_t)f2bf(v.w) << 16);
  *(uint2*)(dst + i * 4) = pk;
}

// ---------- merged Q/K/V projection: 256(M) x 64(N) tile, 512 threads ----------
// 8 waves stacked along M (wave tile 32x64); B tile staged ONCE per step and
// shared by all 8 waves (flash-validated sharing pattern). BK=64, chunk-XOR
// swizzled LDS, 2 barriers/step. FUSED epilogues:
//  p=0 (Q): chunk-LN (*0.125*log2e) + scatter to pre-swizzled attention layout
//  p=1 (K): chunk-LN + scatter
//  p=2 (V): transpose to Vt[bh][hd][n^] bf16 (swizzled for flash LDS staging)
__global__ __launch_bounds__(512) void gemm_qkv(const u16* __restrict__ A0, const u16* __restrict__ A1,
                                                const u16* __restrict__ A2, const u16* __restrict__ B0,
                                                const u16* __restrict__ B1, const u16* __restrict__ B2,
                                                u16* __restrict__ Qout, u16* __restrict__ Kout,
                                                u16* __restrict__ Vout,
                                                const float* __restrict__ qg, const float* __restrict__ qb,
                                                const float* __restrict__ kg, const float* __restrict__ kb) {
  __shared__ __align__(16) u16 Al[256 * 64];   // 32KB
  __shared__ __align__(16) u16 Bl[64 * 64];    // 8KB
  const int p = blockIdx.x >> 8;
  const int b0 = blockIdx.x & 255;
  const int bid = ((b0 & 7) << 5) + (b0 >> 3);    // XCD swizzle, bijective: 256 = 8*32
  const int bm = bid >> 4, bn = bid & 15;
  const u16* A = (p == 0) ? A0 : ((p == 1) ? A1 : A2);
  const u16* B = (p == 0) ? B0 : ((p == 1) ? B1 : B2);

  const int t = threadIdx.x;
  const int w = t >> 6;
  const int lane = t & 63;
  const int l15 = lane & 15, l4 = lane >> 4;

  f32x4 acc[2][4];
#pragma unroll
  for (int i = 0; i < 2; ++i)
#pragma unroll
    for (int j = 0; j < 4; ++j) acc[i][j] = (f32x4){0.f, 0.f, 0.f, 0.f};

  const u16* Ab = A + (size_t)bm * 256 * 1024;
  const u16* Bb = B + (size_t)bn * 64 * 1024;

  for (int kt = 0; kt < 1024; kt += 64) {
    // stage A 32KB (4 passes x 512 thr) + B 8KB (1 pass); LDS dest linear,
    // global source chunk-swizzled (rule #21)
#pragma unroll
    for (int pa = 0; pa < 4; ++pa) {
      const int idx = pa * 512 + t;
      const int row = idx >> 3, ch = idx & 7;
      const int sch = ch ^ (row & 7);
      gld16(Ab + (size_t)row * 1024 + kt + sch * 8, (char*)Al + pa * 8192 + (w << 10));
    }
    {
      const int row = t >> 3, ch = t & 7;
      const int sch = ch ^ (row & 7);
      gld16(Bb + (size_t)row * 1024 + kt + sch * 8, (char*)Bl + (w << 10));
    }
    __syncthreads();
#pragma unroll
    for (int ks = 0; ks < 2; ++ks) {
      bf16x8 af[2], bfr[4];
#pragma unroll
      for (int mi = 0; mi < 2; ++mi) {
        const int row = w * 32 + mi * 16 + l15;
        const int ch = (ks * 4 + l4) ^ (row & 7);
        af[mi] = *(const bf16x8*)&Al[row * 64 + ch * 8];
      }
#pragma unroll
      for (int nj = 0; nj < 4; ++nj) {
        const int row = nj * 16 + l15;
        const int ch = (ks * 4 + l4) ^ (row & 7);
        bfr[nj] = *(const bf16x8*)&Bl[row * 64 + ch * 8];
      }
#pragma unroll
      for (int mi = 0; mi < 2; ++mi)
#pragma unroll
        for (int nj = 0; nj < 4; ++nj)
          acc[mi][nj] = __builtin_amdgcn_mfma_f32_16x16x32_bf16(af[mi], bfr[nj], acc[mi][nj], 0, 0, 0);
    }
    __syncthreads();
  }

  const int c = bn;                               // 64-col chunk index = head index

  if (p == 2) {
    // ---- V transpose epilogue: Vout[(b*16+c)*64+hd][n^swz] ----
#pragma unroll
    for (int mi = 0; mi < 2; ++mi) {
      const int n0 = bm * 256 + w * 32 + mi * 16 + l4 * 4;   // rows r=0..3 consecutive n
      const int bi = n0 >> 10, ni = n0 & 1023;
      const int nt = ni >> 6, ng = (ni >> 3) & 7, no = ni & 7;
#pragma unroll
      for (int nj = 0; nj < 4; ++nj) {
        const int hd = nj * 16 + l15;
        uint32_t w0 = (uint32_t)f2bf(acc[mi][nj][0]) | ((uint32_t)f2bf(acc[mi][nj][1]) << 16);
        uint32_t w1 = (uint32_t)f2bf(acc[mi][nj][2]) | ((uint32_t)f2bf(acc[mi][nj][3]) << 16);
        uint2 pk = {w0, w1};
        const size_t addr = ((size_t)(bi * 16 + c) * 64 + hd) * 1024 + nt * 64 + ((ng ^ (hd & 7)) << 3) + no;
        *(uint2*)(Vout + addr) = pk;
      }
    }
    return;
  }

  // ---- Q/K chunk-LN epilogue ----
  const float scale = (p == 0) ? 0.18033688011112042f : 1.0f;  // Q: 0.125*log2(e)
  const float* gv = (p == 0) ? qg : kg;
  const float* bv = (p == 0) ? qb : kb;
  u16* out = (p == 0) ? Qout : Kout;
  float gl[4], blc[4];
#pragma unroll
  for (int nj = 0; nj < 4; ++nj) {
    gl[nj] = gv[nj * 16 + l15];
    blc[nj] = bv[nj * 16 + l15] * scale;
  }
#pragma unroll
  for (int mi = 0; mi < 2; ++mi) {
#pragma unroll
    for (int r = 0; r < 4; ++r) {
      float s1 = 0.f, s2 = 0.f;
#pragma unroll
      for (int nj = 0; nj < 4; ++nj) {
        const float x = acc[mi][nj][r];
        s1 += x; s2 += x * x;
      }
#pragma unroll
      for (int mk = 1; mk < 16; mk <<= 1) {
        s1 += __shfl_xor(s1, mk, 64);
        s2 += __shfl_xor(s2, mk, 64);
      }
      const float mean = s1 * (1.0f / 64.0f);
      const float var = s2 * (1.0f / 64.0f) - mean * mean;
      const float rr = rsqrtf(var + 1e-5f) * scale;
      const int row_g = bm * 256 + w * 32 + mi * 16 + l4 * 4 + r;
      const int bi = row_g >> 10, rsi = row_g & 1023;
      size_t base; int sw;
      if (p == 0) {   // faithful-reshape Q layout
        const int h = rsi >> 6;
        const int s2i = ((rsi & 63) << 4) + c;
        base = ((size_t)(bi * 16 + h) * 1024 + s2i) * 64;
        sw = (s2i & 7) << 3;
      } else {        // K layout
        base = ((size_t)(bi * 16 + c) * 1024 + rsi) * 64;
        sw = (rsi & 7) << 3;
      }
#pragma unroll
      for (int nj = 0; nj < 4; ++nj) {
        const float y = (acc[mi][nj][r] - mean) * rr * gl[nj] + blc[nj];
        out[base + ((nj * 16 + l15) ^ sw)] = f2bf(y);
      }
    }
  }
}

// output projection: 128x64 tile, 256 threads (validated round-14 config)
__global__ __launch_bounds__(256) void gemm_p(const u16* __restrict__ A, const u16* __restrict__ B,
                                              float* __restrict__ C) {
  __shared__ __align__(16) u16 Al[128 * 64];
  __shared__ __align__(16) u16 Bl[64 * 64];
  const int bid = ((blockIdx.x & 7) << 6) + (blockIdx.x >> 3);
  const int bm = bid >> 4, bn = bid & 15;
  const int t = threadIdx.x;
  const int w = t >> 6;
  const int lane = t & 63;
  const int l15 = lane & 15, l4 = lane >> 4;

  f32x4 acc[2][4];
#pragma unroll
  for (int i = 0; i < 2; ++i)
#pragma unroll
    for (int j = 0; j < 4; ++j) acc[i][j] = (f32x4){0.f, 0.f, 0.f, 0.f};

  const u16* Ab = A + (size_t)bm * 128 * 1024;
  const u16* Bb = B + (size_t)bn * 64 * 1024;

  for (int kt = 0; kt < 1024; kt += 64) {
#pragma unroll
    for (int p = 0; p < 4; ++p) {
      const int idx = p * 256 + t;
      const int row = idx >> 3, ch = idx & 7;
      const int sch = ch ^ (row & 7);
      gld16(Ab + (size_t)row * 1024 + kt + sch * 8, (char*)Al + p * 4096 + (w << 10));
    }
#pragma unroll
    for (int p = 0; p < 2; ++p) {
      const int idx = p * 256 + t;
      const int row = idx >> 3, ch = idx & 7;
      const int sch = ch ^ (row & 7);
      gld16(Bb + (size_t)row * 1024 + kt + sch * 8, (char*)Bl + p * 4096 + (w << 10));
    }
    __syncthreads();
#pragma unroll
    for (int ks = 0; ks < 2; ++ks) {
      bf16x8 af[2], bfr[4];
#pragma unroll
      for (int mi = 0; mi < 2; ++mi) {
        const int row = w * 32 + mi * 16 + l15;
        const int ch = (ks * 4 + l4) ^ (row & 7);
        af[mi] = *(const bf16x8*)&Al[row * 64 + ch * 8];
      }
#pragma unroll
      for (int nj = 0; nj < 4; ++nj) {
        const int row = nj * 16 + l15;
        const int ch = (ks * 4 + l4) ^ (row & 7);
        bfr[nj] = *(const bf16x8*)&Bl[row * 64 + ch * 8];
      }
#pragma unroll
      for (int mi = 0; mi < 2; ++mi)
#pragma unroll
        for (int nj = 0; nj < 4; ++nj)
          acc[mi][nj] = __builtin_amdgcn_mfma_f32_16x16x32_bf16(af[mi], bfr[nj], acc[mi][nj], 0, 0, 0);
    }
    __syncthreads();
  }

  float* Cb = C + (size_t)bm * 128 * 1024 + bn * 64;
#pragma unroll
  for (int mi = 0; mi < 2; ++mi)
#pragma unroll
    for (int nj = 0; nj < 4; ++nj) {
      const int row = w * 32 + mi * 16 + l4 * 4;
      const int col = nj * 16 + l15;
#pragma unroll
      for (int r = 0; r < 4; ++r)
        Cb[(size_t)(row + r) * 1024 + col] = acc[mi][nj][r];
    }
}

// ---------- flash attention: 512 threads, 2 q-strips share one K/V staging ----------
// Waves 0-3 -> strip 0 (q rows qt2*128..+64), waves 4-7 -> strip 1 (+64..128).
// exp2-domain softmax (no max/rescale), ones-column denominator, bf16 output,
// T5 setprio around MFMA clusters.
__global__ __launch_bounds__(512) void flash(const u16* __restrict__ Q,
                                             const u16* __restrict__ Km,
                                             const u16* __restrict__ Vt,
                                             u16* __restrict__ ctxb) {
  __shared__ __align__(16) u16 Kl[2 * 64 * 64];
  __shared__ __align__(16) u16 Vl[2 * 64 * 64];
  __shared__ __align__(16) u16 Pl[2 * 64 * 64];   // one 64x64 P per strip
  // XCD swizzle: 8 q-blocks of one bh land on one XCD (512 = 8*64)
  const int bid = ((blockIdx.x & 7) << 6) + (blockIdx.x >> 3);
  const int bh = bid >> 3, qt2 = bid & 7;
  const int t = threadIdx.x, w = t >> 6, lane = t & 63;
  const int s = w >> 2, ws = w & 3;               // strip, wave-in-strip
  const int l15 = lane & 15, l4 = lane >> 4;
  const int sx = (l15 & 7) << 3;
  const int ea0 = (l4 * 8) ^ sx;
  const int ea1 = ea0 ^ 32;

  // Q hoisted to registers (global is pre-swizzled identically to LDS layout)
  const u16* Qrow = Q + ((size_t)bh * 1024 + qt2 * 128 + s * 64 + ws * 16 + l15) * 64;
  const bf16x8 aq0 = *(const bf16x8*)(Qrow + ea0);
  const bf16x8 aq1 = *(const bf16x8*)(Qrow + ea1);
  const bf16x8 vone = {0x3F80, 0x3F80, 0x3F80, 0x3F80, 0x3F80, 0x3F80, 0x3F80, 0x3F80};

  const u16* Kg = Km + (size_t)bh * 65536;
  const u16* Vg = Vt + (size_t)bh * 65536;
  u16* Ps = Pl + s * 4096;

  // prologue: stage tile 0 -> buf 0 (one 512-thread pass per operand)
  gld16((const char*)Kg + t * 16, (char*)Kl + (w << 10));
  gld16(Vg + (t >> 3) * 1024 + (t & 7) * 8, (char*)Vl + (w << 10));
  __syncthreads();

  f32x4 o[4];
  for (int i = 0; i < 4; ++i) o[i] = (f32x4){0.f, 0.f, 0.f, 0.f};
  f32x4 o4 = (f32x4){0.f, 0.f, 0.f, 0.f};   // row sums (denominator)

  int cur = 0;
  for (int nt2 = 0; nt2 < 16; ++nt2) {
    // prefetch next tile into other buffer (issue-early; drained at end-of-iter sync)
    if (nt2 < 15) {
      const int nb = (cur ^ 1) * 8192;
      gld16((const char*)(Kg + (size_t)(nt2 + 1) * 4096) + t * 16, (char*)Kl + nb + (w << 10));
      gld16(Vg + (t >> 3) * 1024 + (nt2 + 1) * 64 + (t & 7) * 8, (char*)Vl + nb + (w << 10));
    }
    const u16* Kc = Kl + cur * 4096;
    const u16* Vc = Vl + cur * 4096;

    // QK^T: wave owns score rows ws*16..+16 of its strip, all 64 cols (log2-domain)
    f32x4 sc[4];
    for (int cj = 0; cj < 4; ++cj) sc[cj] = (f32x4){0.f, 0.f, 0.f, 0.f};
    __builtin_amdgcn_s_setprio(1);
#pragma unroll
    for (int ks = 0; ks < 2; ++ks) {
      const int ea = ks ? ea1 : ea0;
      const bf16x8 aq = ks ? aq1 : aq0;
#pragma unroll
      for (int cj = 0; cj < 4; ++cj) {
        bf16x8 bk = *(const bf16x8*)&Kc[(cj * 16 + l15) * 64 + ea];
        sc[cj] = __builtin_amdgcn_mfma_f32_16x16x32_bf16(aq, bk, sc[cj], 0, 0, 0);
      }
    }
    __builtin_amdgcn_s_setprio(0);

    // p = exp2(sc); write P strip (per-wave private rows, swizzled). No max/rescale.
#pragma unroll
    for (int cj = 0; cj < 4; ++cj)
#pragma unroll
      for (int r = 0; r < 4; ++r) {
        const float pf = __builtin_amdgcn_exp2f(sc[cj][r]);
        const uint32_t u = __builtin_bit_cast(uint32_t, pf);
        const int prow = ws * 16 + l4 * 4 + r;
        Ps[prow * 64 + ((cj * 16 + l15) ^ (((l4 * 4 + r) & 7) << 3))] = (u16)((u + 0x8000u) >> 16);
      }

    // PV + ones-column row-sum
    __builtin_amdgcn_s_setprio(1);
#pragma unroll
    for (int ks = 0; ks < 2; ++ks) {
      const int ea = ks ? ea1 : ea0;
      bf16x8 ap = *(const bf16x8*)&Ps[(ws * 16 + l15) * 64 + ea];
#pragma unroll
      for (int c2 = 0; c2 < 4; ++c2) {
        bf16x8 bv = *(const bf16x8*)&Vc[(c2 * 16 + l15) * 64 + ea];
        o[c2] = __builtin_amdgcn_mfma_f32_16x16x32_bf16(ap, bv, o[c2], 0, 0, 0);
      }
      o4 = __builtin_amdgcn_mfma_f32_16x16x32_bf16(ap, vone, o4, 0, 0, 0);
    }
    __builtin_amdgcn_s_setprio(0);
    // single full sync per tile: drains prefetch (vmcnt) + all LDS ops, then barrier
    __syncthreads();
    cur ^= 1;
  }

  const int b = bh >> 4, h = bh & 15;
#pragma unroll
  for (int c2 = 0; c2 < 4; ++c2) {
#pragma unroll
    for (int r = 0; r < 4; ++r) {
      const int s2 = qt2 * 128 + s * 64 + ws * 16 + l4 * 4 + r;
      const int hd = c2 * 16 + l15;
      ctxb[((size_t)b * 1024 + s2) * 1024 + h * 64 + hd] = f2bf(o[c2][r] / o4[r]);
    }
  }
}

// ---------- full-row LayerNorm (D=1024), bf16 in -> bf16 out ----------
__global__ __launch_bounds__(256) void ln_row(const u16* __restrict__ X,
                                              const float* __restrict__ g,
                                              const float* __restrict__ bb,
                                              u16* __restrict__ out) {
  __shared__ float red[8];
  const int row = blockIdx.x, t = threadIdx.x;
  const int w = t >> 6, lane = t & 63;
  const u16* xr = X + (size_t)row * 1024;
  ushort4 uv = *(const ushort4*)(xr + t * 4);
  float x0 = __builtin_bit_cast(float, (uint32_t)uv.x << 16);
  float x1 = __builtin_bit_cast(float, (uint32_t)uv.y << 16);
  float x2 = __builtin_bit_cast(float, (uint32_t)uv.z << 16);
  float x3 = __builtin_bit_cast(float, (uint32_t)uv.w << 16);
  float s = x0 + x1 + x2 + x3;
  for (int mk = 1; mk < 64; mk <<= 1) s += __shfl_xor(s, mk, 64);
  if (lane == 0) red[w] = s;
  __syncthreads();
  const float mean = (red[0] + red[1] + red[2] + red[3]) * (1.0f / 1024.0f);
  const float dx = x0 - mean, dy = x1 - mean, dz = x2 - mean, dw = x3 - mean;
  float q = dx * dx + dy * dy + dz * dz + dw * dw;
  for (int mk = 1; mk < 64; mk <<= 1) q += __shfl_xor(q, mk, 64);
  if (lane == 0) red[4 + w] = q;
  __syncthreads();
  const float var = (red[4] + red[5] + red[6] + red[7]) * (1.0f / 1024.0f);
  const float rs = rsqrtf(var + 1e-5f);
  float4 gg = *(const float4*)(g + t * 4);
  float4 b4 = *(const float4*)(bb + t * 4);
  uint2 pk;
  pk.x = (uint32_t)f2bf(dx * rs * gg.x + b4.x) | ((uint32_t)f2bf(dy * rs * gg.y + b4.y) << 16);
  pk.y = (uint32_t)f2bf(dz * rs * gg.z + b4.z) | ((uint32_t)f2bf(dw * rs * gg.w + b4.w) << 16);
  *(uint2*)(out + (size_t)row * 1024 + t * 4) = pk;
}

// ---------- launcher ----------
extern "C" void kernel_launch(void* const* d_in, const int* in_sizes, int n_in,
                              void* d_out, int out_size, void* d_ws, size_t ws_size,
                              hipStream_t stream) {
  (void)in_sizes; (void)n_in; (void)out_size; (void)ws_size;
  const float* x_q = (const float*)d_in[0];
  const float* x_k = (const float*)d_in[1];
  const float* x_v = (const float*)d_in[2];
  const float* Wq  = (const float*)d_in[3];
  const float* Wk  = (const float*)d_in[4];
  const float* Wv  = (const float*)d_in[5];
  const float* Wp  = (const float*)d_in[6];
  const float* qn_g = (const float*)d_in[7];
  const float* qn_b = (const float*)d_in[8];
  const float* kn_g = (const float*)d_in[9];
  const float* kn_b = (const float*)d_in[10];
  const float* on_g = (const float*)d_in[11];
  const float* on_b = (const float*)d_in[12];

  char* ws = (char*)d_ws;
  u16* xq_bf = (u16*)(ws + (0ull << 20));
  u16* xk_bf = (u16*)(ws + (8ull << 20));
  u16* xv_bf = (u16*)(ws + (16ull << 20));
  u16* Wq_bf = (u16*)(ws + (24ull << 20));
  u16* Wk_bf = (u16*)(ws + (26ull << 20));
  u16* Wv_bf = (u16*)(ws + (28ull << 20));
  u16* Wp_bf = (u16*)(ws + (30ull << 20));
  u16* Qa   = (u16*)(ws + (32ull << 20));
  u16* Ka   = (u16*)(ws + (40ull << 20));
  u16* Vtb  = (u16*)(ws + (48ull << 20));
  u16* ctxb = (u16*)(ws + (56ull << 20));   // bf16 attention output
  u16* ctx2 = (u16*)(ws + (64ull << 20));   // bf16 LN'd output

  cast_all<<<16384, 256, 0, stream>>>(x_q, x_k, x_v, Wq, Wk, Wv, Wp,
                                      xq_bf, xk_bf, xv_bf, Wq_bf, Wk_bf, Wv_bf, Wp_bf);

  // fused Q/K/V projections + LN/scatter/transpose epilogues (768 blocks x 512 thr)
  gemm_qkv<<<768, 512, 0, stream>>>(xq_bf, xk_bf, xv_bf, Wq_bf, Wk_bf, Wv_bf,
                                    Qa, Ka, Vtb, qn_g, qn_b, kn_g, kn_b);
  // attention -> ctx bf16 (512 blocks x 512 threads, 2 q-strips/block)
  flash<<<512, 512, 0, stream>>>(Qa, Ka, Vtb, ctxb);
  // output LN + projection
  ln_row<<<4096, 256, 0, stream>>>(ctxb, on_g, on_b, ctx2);
  gemm_p<<<512, 256, 0, stream>>>(ctx2, Wp_bf, (float*)d_out);
}

// Round 19
// 106.568 us; speedup vs baseline: 1.0294x; 1.0294x over previous
//
#include <hip/hip_runtime.h>
#include <cstdint>

typedef unsigned short u16;
typedef __attribute__((ext_vector_type(4))) float f32x4;
typedef __attribute__((ext_vector_type(8))) short bf16x8;

// ---------- helpers ----------
__device__ __forceinline__ u16 f2bf(float f) {
  uint32_t u = __builtin_bit_cast(uint32_t, f);
  u += 0x7FFFu + ((u >> 16) & 1u);   // RNE
  return (u16)(u >> 16);
}

__device__ __forceinline__ void gld16(const void* g, void* l) {
  __builtin_amdgcn_global_load_lds((const __attribute__((address_space(1))) void*)g,
                                   (__attribute__((address_space(3))) void*)l,
                                   16, 0, 0);
}

// ---------- all f32->bf16 casts in one launch ----------
__global__ __launch_bounds__(256) void cast_all(const float* __restrict__ xq, const float* __restrict__ xk,
                                                const float* __restrict__ xv, const float* __restrict__ Wq,
                                                const float* __restrict__ Wk, const float* __restrict__ Wv,
                                                const float* __restrict__ Wp,
                                                u16* __restrict__ oq, u16* __restrict__ ok, u16* __restrict__ ov,
                                                u16* __restrict__ owq, u16* __restrict__ owk,
                                                u16* __restrict__ owv, u16* __restrict__ owp) {
  int bid = blockIdx.x;
  const float* src; u16* dst; size_t i;
  if (bid < 12288) {              // 3 x tensors, 4096 blocks each
    const int p = bid >> 12, ib = bid & 4095;
    src = (p == 0) ? xq : ((p == 1) ? xk : xv);
    dst = (p == 0) ? oq : ((p == 1) ? ok : ov);
    i = (size_t)ib * 256 + threadIdx.x;
  } else {                        // 4 weights, 1024 blocks each
    bid -= 12288;
    const int p = bid >> 10, ib = bid & 1023;
    src = (p == 0) ? Wq : ((p == 1) ? Wk : ((p == 2) ? Wv : Wp));
    dst = (p == 0) ? owq : ((p == 1) ? owk : ((p == 2) ? owv : owp));
    i = (size_t)ib * 256 + threadIdx.x;
  }
  float4 v = *(const float4*)(src + i * 4);
  uint2 pk;
  pk.x = (uint32_t)f2bf(v.x) | ((uint32_t)f2bf(v.y) << 16);
  pk.y = (uint32_t)f2bf(v.z) | ((uint32_t)f2bf(v.w) << 16);
  *(uint2*)(dst + i * 4) = pk;
}

// ---------- GEMM main loop: 128(M) x 64(N) tile, BK=64, chunk-XOR swizzled LDS ----------
// 4 waves stacked along M (wave tile 32x64). Single-buffered, 2 barriers/step.
// Round-14/17-validated local optimum of the 2-phase template.
__device__ __forceinline__ void gemm_mainloop(const u16* __restrict__ A, const u16* __restrict__ B,
                                              int bm, int bn, u16* Al, u16* Bl,
                                              f32x4 (&acc)[2][4]) {
  const int t = threadIdx.x;
  const int w = t >> 6;
  const int lane = t & 63;
  const int l15 = lane & 15, l4 = lane >> 4;

  const u16* Ab = A + (size_t)bm * 128 * 1024;
  const u16* Bb = B + (size_t)bn * 64 * 1024;

  for (int kt = 0; kt < 1024; kt += 64) {
    // stage A 16KB (4 passes) + B 8KB (2 passes); LDS dest linear,
    // global source chunk-swizzled (rule #21)
#pragma unroll
    for (int p = 0; p < 4; ++p) {
      const int idx = p * 256 + t;
      const int row = idx >> 3, ch = idx & 7;
      const int sch = ch ^ (row & 7);
      gld16(Ab + (size_t)row * 1024 + kt + sch * 8, (char*)Al + p * 4096 + (w << 10));
    }
#pragma unroll
    for (int p = 0; p < 2; ++p) {
      const int idx = p * 256 + t;
      const int row = idx >> 3, ch = idx & 7;
      const int sch = ch ^ (row & 7);
      gld16(Bb + (size_t)row * 1024 + kt + sch * 8, (char*)Bl + p * 4096 + (w << 10));
    }
    __syncthreads();
#pragma unroll
    for (int ks = 0; ks < 2; ++ks) {
      bf16x8 af[2], bfr[4];
#pragma unroll
      for (int mi = 0; mi < 2; ++mi) {
        const int row = w * 32 + mi * 16 + l15;
        const int ch = (ks * 4 + l4) ^ (row & 7);
        af[mi] = *(const bf16x8*)&Al[row * 64 + ch * 8];
      }
#pragma unroll
      for (int nj = 0; nj < 4; ++nj) {
        const int row = nj * 16 + l15;
        const int ch = (ks * 4 + l4) ^ (row & 7);
        bfr[nj] = *(const bf16x8*)&Bl[row * 64 + ch * 8];
      }
#pragma unroll
      for (int mi = 0; mi < 2; ++mi)
#pragma unroll
        for (int nj = 0; nj < 4; ++nj)
          acc[mi][nj] = __builtin_amdgcn_mfma_f32_16x16x32_bf16(af[mi], bfr[nj], acc[mi][nj], 0, 0, 0);
    }
    __syncthreads();
  }
}

// merged Q/K/V projection with FUSED epilogues (tile = 128 rows x one 64-col head chunk):
//  p=0 (Q): chunk-LN (*0.125*log2e) + scatter to pre-swizzled attention layout
//  p=1 (K): chunk-LN + scatter
//  p=2 (V): transpose to Vt[bh][hd][n^] bf16 (swizzled for flash LDS staging)
__global__ __launch_bounds__(256) void gemm_qkv(const u16* __restrict__ A0, const u16* __restrict__ A1,
                                                const u16* __restrict__ A2, const u16* __restrict__ B0,
                                                const u16* __restrict__ B1, const u16* __restrict__ B2,
                                                u16* __restrict__ Qout, u16* __restrict__ Kout,
                                                u16* __restrict__ Vout,
                                                const float* __restrict__ qg, const float* __restrict__ qb,
                                                const float* __restrict__ kg, const float* __restrict__ kb) {
  __shared__ __align__(16) u16 Al[128 * 64];
  __shared__ __align__(16) u16 Bl[64 * 64];
  const int p = blockIdx.x >> 9;
  const int b0 = blockIdx.x & 511;
  const int bid = ((b0 & 7) << 6) + (b0 >> 3);    // XCD swizzle, bijective: 512 = 8*64
  const int bm = bid >> 4, bn = bid & 15;
  const u16* A = (p == 0) ? A0 : ((p == 1) ? A1 : A2);
  const u16* B = (p == 0) ? B0 : ((p == 1) ? B1 : B2);

  f32x4 acc[2][4];
#pragma unroll
  for (int i = 0; i < 2; ++i)
#pragma unroll
    for (int j = 0; j < 4; ++j) acc[i][j] = (f32x4){0.f, 0.f, 0.f, 0.f};

  gemm_mainloop(A, B, bm, bn, Al, Bl, acc);

  const int t = threadIdx.x, w = t >> 6, lane = t & 63;
  const int l15 = lane & 15, l4 = lane >> 4;
  const int c = bn;                               // 64-col chunk index = head index

  if (p == 2) {
    // ---- V transpose epilogue: Vout[(b*16+c)*64+hd][n^swz] ----
#pragma unroll
    for (int mi = 0; mi < 2; ++mi) {
      const int n0 = bm * 128 + w * 32 + mi * 16 + l4 * 4;   // rows r=0..3 consecutive n
      const int bi = n0 >> 10, ni = n0 & 1023;
      const int nt = ni >> 6, ng = (ni >> 3) & 7, no = ni & 7;
#pragma unroll
      for (int nj = 0; nj < 4; ++nj) {
        const int hd = nj * 16 + l15;
        uint32_t w0 = (uint32_t)f2bf(acc[mi][nj][0]) | ((uint32_t)f2bf(acc[mi][nj][1]) << 16);
        uint32_t w1 = (uint32_t)f2bf(acc[mi][nj][2]) | ((uint32_t)f2bf(acc[mi][nj][3]) << 16);
        uint2 pk = {w0, w1};
        const size_t addr = ((size_t)(bi * 16 + c) * 64 + hd) * 1024 + nt * 64 + ((ng ^ (hd & 7)) << 3) + no;
        *(uint2*)(Vout + addr) = pk;
      }
    }
    return;
  }

  // ---- Q/K chunk-LN epilogue ----
  const float scale = (p == 0) ? 0.18033688011112042f : 1.0f;  // Q: 0.125*log2(e)
  const float* gv = (p == 0) ? qg : kg;
  const float* bv = (p == 0) ? qb : kb;
  u16* out = (p == 0) ? Qout : Kout;
  float gl[4], blc[4];
#pragma unroll
  for (int nj = 0; nj < 4; ++nj) {
    gl[nj] = gv[nj * 16 + l15];
    blc[nj] = bv[nj * 16 + l15] * scale;
  }
#pragma unroll
  for (int mi = 0; mi < 2; ++mi) {
#pragma unroll
    for (int r = 0; r < 4; ++r) {
      float s1 = 0.f, s2 = 0.f;
#pragma unroll
      for (int nj = 0; nj < 4; ++nj) {
        const float x = acc[mi][nj][r];
        s1 += x; s2 += x * x;
      }
#pragma unroll
      for (int mk = 1; mk < 16; mk <<= 1) {
        s1 += __shfl_xor(s1, mk, 64);
        s2 += __shfl_xor(s2, mk, 64);
      }
      const float mean = s1 * (1.0f / 64.0f);
      const float var = s2 * (1.0f / 64.0f) - mean * mean;
      const float rr = rsqrtf(var + 1e-5f) * scale;
      const int row_g = bm * 128 + w * 32 + mi * 16 + l4 * 4 + r;
      const int bi = row_g >> 10, rsi = row_g & 1023;
      size_t base; int sw;
      if (p == 0) {   // faithful-reshape Q layout
        const int h = rsi >> 6;
        const int s2i = ((rsi & 63) << 4) + c;
        base = ((size_t)(bi * 16 + h) * 1024 + s2i) * 64;
        sw = (s2i & 7) << 3;
      } else {        // K layout
        base = ((size_t)(bi * 16 + c) * 1024 + rsi) * 64;
        sw = (rsi & 7) << 3;
      }
#pragma unroll
      for (int nj = 0; nj < 4; ++nj) {
        const float y = (acc[mi][nj][r] - mean) * rr * gl[nj] + blc[nj];
        out[base + ((nj * 16 + l15) ^ sw)] = f2bf(y);
      }
    }
  }
}

// output projection: plain f32 C write (128x64 tiling, 512 blocks)
__global__ __launch_bounds__(256) void gemm_p(const u16* __restrict__ A, const u16* __restrict__ B,
                                              float* __restrict__ C) {
  __shared__ __align__(16) u16 Al[128 * 64];
  __shared__ __align__(16) u16 Bl[64 * 64];
  const int bid = ((blockIdx.x & 7) << 6) + (blockIdx.x >> 3);
  const int bm = bid >> 4, bn = bid & 15;

  f32x4 acc[2][4];
#pragma unroll
  for (int i = 0; i < 2; ++i)
#pragma unroll
    for (int j = 0; j < 4; ++j) acc[i][j] = (f32x4){0.f, 0.f, 0.f, 0.f};

  gemm_mainloop(A, B, bm, bn, Al, Bl, acc);

  const int t = threadIdx.x, w = t >> 6, lane = t & 63;
  const int l15 = lane & 15, l4 = lane >> 4;
  float* Cb = C + (size_t)bm * 128 * 1024 + bn * 64;
#pragma unroll
  for (int mi = 0; mi < 2; ++mi)
#pragma unroll
    for (int nj = 0; nj < 4; ++nj) {
      const int row = w * 32 + mi * 16 + l4 * 4;
      const int col = nj * 16 + l15;
#pragma unroll
      for (int r = 0; r < 4; ++r)
        Cb[(size_t)(row + r) * 1024 + col] = acc[mi][nj][r];
    }
}

// ---------- flash attention: 512 threads, 2 q-strips share one K/V staging ----------
// Waves 0-3 -> strip 0 (q rows qt2*128..+64), waves 4-7 -> strip 1 (+64..128).
// exp2-domain softmax (no max/rescale; |score*ln2|<=8 by LN construction),
// ones-column MFMA denominator, bf16 output, T5 setprio around MFMA clusters.
__global__ __launch_bounds__(512) void flash(const u16* __restrict__ Q,
                                             const u16* __restrict__ Km,
                                             const u16* __restrict__ Vt,
                                             u16* __restrict__ ctxb) {
  __shared__ __align__(16) u16 Kl[2 * 64 * 64];
  __shared__ __align__(16) u16 Vl[2 * 64 * 64];
  __shared__ __align__(16) u16 Pl[2 * 64 * 64];   // one 64x64 P per strip
  // XCD swizzle: 8 q-blocks of one bh land on one XCD (512 = 8*64)
  const int bid = ((blockIdx.x & 7) << 6) + (blockIdx.x >> 3);
  const int bh = bid >> 3, qt2 = bid & 7;
  const int t = threadIdx.x, w = t >> 6, lane = t & 63;
  const int s = w >> 2, ws = w & 3;               // strip, wave-in-strip
  const int l15 = lane & 15, l4 = lane >> 4;
  const int sx = (l15 & 7) << 3;
  const int ea0 = (l4 * 8) ^ sx;
  const int ea1 = ea0 ^ 32;

  // Q hoisted to registers (global is pre-swizzled identically to LDS layout)
  const u16* Qrow = Q + ((size_t)bh * 1024 + qt2 * 128 + s * 64 + ws * 16 + l15) * 64;
  const bf16x8 aq0 = *(const bf16x8*)(Qrow + ea0);
  const bf16x8 aq1 = *(const bf16x8*)(Qrow + ea1);
  const bf16x8 vone = {0x3F80, 0x3F80, 0x3F80, 0x3F80, 0x3F80, 0x3F80, 0x3F80, 0x3F80};

  const u16* Kg = Km + (size_t)bh * 65536;
  const u16* Vg = Vt + (size_t)bh * 65536;
  u16* Ps = Pl + s * 4096;

  // prologue: stage tile 0 -> buf 0 (one 512-thread pass per operand)
  gld16((const char*)Kg + t * 16, (char*)Kl + (w << 10));
  gld16(Vg + (t >> 3) * 1024 + (t & 7) * 8, (char*)Vl + (w << 10));
  __syncthreads();

  f32x4 o[4];
  for (int i = 0; i < 4; ++i) o[i] = (f32x4){0.f, 0.f, 0.f, 0.f};
  f32x4 o4 = (f32x4){0.f, 0.f, 0.f, 0.f};   // row sums (denominator)

  int cur = 0;
  for (int nt2 = 0; nt2 < 16; ++nt2) {
    // prefetch next tile into other buffer (issue-early; drained at end-of-iter sync)
    if (nt2 < 15) {
      const int nb = (cur ^ 1) * 8192;
      gld16((const char*)(Kg + (size_t)(nt2 + 1) * 4096) + t * 16, (char*)Kl + nb + (w << 10));
      gld16(Vg + (t >> 3) * 1024 + (nt2 + 1) * 64 + (t & 7) * 8, (char*)Vl + nb + (w << 10));
    }
    const u16* Kc = Kl + cur * 4096;
    const u16* Vc = Vl + cur * 4096;

    // QK^T: wave owns score rows ws*16..+16 of its strip, all 64 cols (log2-domain)
    f32x4 sc[4];
    for (int cj = 0; cj < 4; ++cj) sc[cj] = (f32x4){0.f, 0.f, 0.f, 0.f};
    __builtin_amdgcn_s_setprio(1);
#pragma unroll
    for (int ks = 0; ks < 2; ++ks) {
      const int ea = ks ? ea1 : ea0;
      const bf16x8 aq = ks ? aq1 : aq0;
#pragma unroll
      for (int cj = 0; cj < 4; ++cj) {
        bf16x8 bk = *(const bf16x8*)&Kc[(cj * 16 + l15) * 64 + ea];
        sc[cj] = __builtin_amdgcn_mfma_f32_16x16x32_bf16(aq, bk, sc[cj], 0, 0, 0);
      }
    }
    __builtin_amdgcn_s_setprio(0);

    // p = exp2(sc); write P strip (per-wave private rows, swizzled). No max/rescale.
#pragma unroll
    for (int cj = 0; cj < 4; ++cj)
#pragma unroll
      for (int r = 0; r < 4; ++r) {
        const float pf = __builtin_amdgcn_exp2f(sc[cj][r]);
        const uint32_t u = __builtin_bit_cast(uint32_t, pf);
        const int prow = ws * 16 + l4 * 4 + r;
        Ps[prow * 64 + ((cj * 16 + l15) ^ (((l4 * 4 + r) & 7) << 3))] = (u16)((u + 0x8000u) >> 16);
      }

    // PV + ones-column row-sum
    __builtin_amdgcn_s_setprio(1);
#pragma unroll
    for (int ks = 0; ks < 2; ++ks) {
      const int ea = ks ? ea1 : ea0;
      bf16x8 ap = *(const bf16x8*)&Ps[(ws * 16 + l15) * 64 + ea];
#pragma unroll
      for (int c2 = 0; c2 < 4; ++c2) {
        bf16x8 bv = *(const bf16x8*)&Vc[(c2 * 16 + l15) * 64 + ea];
        o[c2] = __builtin_amdgcn_mfma_f32_16x16x32_bf16(ap, bv, o[c2], 0, 0, 0);
      }
      o4 = __builtin_amdgcn_mfma_f32_16x16x32_bf16(ap, vone, o4, 0, 0, 0);
    }
    __builtin_amdgcn_s_setprio(0);
    // single full sync per tile: drains prefetch (vmcnt) + all LDS ops, then barrier
    __syncthreads();
    cur ^= 1;
  }

  const int b = bh >> 4, h = bh & 15;
#pragma unroll
  for (int c2 = 0; c2 < 4; ++c2) {
#pragma unroll
    for (int r = 0; r < 4; ++r) {
      const int s2 = qt2 * 128 + s * 64 + ws * 16 + l4 * 4 + r;
      const int hd = c2 * 16 + l15;
      ctxb[((size_t)b * 1024 + s2) * 1024 + h * 64 + hd] = f2bf(o[c2][r] / o4[r]);
    }
  }
}

// ---------- full-row LayerNorm (D=1024), bf16 in -> bf16 out ----------
__global__ __launch_bounds__(256) void ln_row(const u16* __restrict__ X,
                                              const float* __restrict__ g,
                                              const float* __restrict__ bb,
                                              u16* __restrict__ out) {
  __shared__ float red[8];
  const int row = blockIdx.x, t = threadIdx.x;
  const int w = t >> 6, lane = t & 63;
  const u16* xr = X + (size_t)row * 1024;
  ushort4 uv = *(const ushort4*)(xr + t * 4);
  float x0 = __builtin_bit_cast(float, (uint32_t)uv.x << 16);
  float x1 = __builtin_bit_cast(float, (uint32_t)uv.y << 16);
  float x2 = __builtin_bit_cast(float, (uint32_t)uv.z << 16);
  float x3 = __builtin_bit_cast(float, (uint32_t)uv.w << 16);
  float s = x0 + x1 + x2 + x3;
  for (int mk = 1; mk < 64; mk <<= 1) s += __shfl_xor(s, mk, 64);
  if (lane == 0) red[w] = s;
  __syncthreads();
  const float mean = (red[0] + red[1] + red[2] + red[3]) * (1.0f / 1024.0f);
  const float dx = x0 - mean, dy = x1 - mean, dz = x2 - mean, dw = x3 - mean;
  float q = dx * dx + dy * dy + dz * dz + dw * dw;
  for (int mk = 1; mk < 64; mk <<= 1) q += __shfl_xor(q, mk, 64);
  if (lane == 0) red[4 + w] = q;
  __syncthreads();
  const float var = (red[4] + red[5] + red[6] + red[7]) * (1.0f / 1024.0f);
  const float rs = rsqrtf(var + 1e-5f);
  float4 gg = *(const float4*)(g + t * 4);
  float4 b4 = *(const float4*)(bb + t * 4);
  uint2 pk;
  pk.x = (uint32_t)f2bf(dx * rs * gg.x + b4.x) | ((uint32_t)f2bf(dy * rs * gg.y + b4.y) << 16);
  pk.y = (uint32_t)f2bf(dz * rs * gg.z + b4.z) | ((uint32_t)f2bf(dw * rs * gg.w + b4.w) << 16);
  *(uint2*)(out + (size_t)row * 1024 + t * 4) = pk;
}

// ---------- launcher ----------
extern "C" void kernel_launch(void* const* d_in, const int* in_sizes, int n_in,
                              void* d_out, int out_size, void* d_ws, size_t ws_size,
                              hipStream_t stream) {
  (void)in_sizes; (void)n_in; (void)out_size; (void)ws_size;
  const float* x_q = (const float*)d_in[0];
  const float* x_k = (const float*)d_in[1];
  const float* x_v = (const float*)d_in[2];
  const float* Wq  = (const float*)d_in[3];
  const float* Wk  = (const float*)d_in[4];
  const float* Wv  = (const float*)d_in[5];
  const float* Wp  = (const float*)d_in[6];
  const float* qn_g = (const float*)d_in[7];
  const float* qn_b = (const float*)d_in[8];
  const float* kn_g = (const float*)d_in[9];
  const float* kn_b = (const float*)d_in[10];
  const float* on_g = (const float*)d_in[11];
  const float* on_b = (const float*)d_in[12];

  char* ws = (char*)d_ws;
  u16* xq_bf = (u16*)(ws + (0ull << 20));
  u16* xk_bf = (u16*)(ws + (8ull << 20));
  u16* xv_bf = (u16*)(ws + (16ull << 20));
  u16* Wq_bf = (u16*)(ws + (24ull << 20));
  u16* Wk_bf = (u16*)(ws + (26ull << 20));
  u16* Wv_bf = (u16*)(ws + (28ull << 20));
  u16* Wp_bf = (u16*)(ws + (30ull << 20));
  u16* Qa   = (u16*)(ws + (32ull << 20));
  u16* Ka   = (u16*)(ws + (40ull << 20));
  u16* Vtb  = (u16*)(ws + (48ull << 20));
  u16* ctxb = (u16*)(ws + (56ull << 20));   // bf16 attention output
  u16* ctx2 = (u16*)(ws + (64ull << 20));   // bf16 LN'd output

  cast_all<<<16384, 256, 0, stream>>>(x_q, x_k, x_v, Wq, Wk, Wv, Wp,
                                      xq_bf, xk_bf, xv_bf, Wq_bf, Wk_bf, Wv_bf, Wp_bf);

  // fused Q/K/V projections + LN/scatter/transpose epilogues (1536 blocks)
  gemm_qkv<<<1536, 256, 0, stream>>>(xq_bf, xk_bf, xv_bf, Wq_bf, Wk_bf, Wv_bf,
                                     Qa, Ka, Vtb, qn_g, qn_b, kn_g, kn_b);
  // attention -> ctx bf16 (512 blocks x 512 threads, 2 q-strips/block)
  flash<<<512, 512, 0, stream>>>(Qa, Ka, Vtb, ctxb);
  // output LN + projection
  ln_row<<<4096, 256, 0, stream>>>(ctxb, on_g, on_b, ctx2);
  gemm_p<<<512, 256, 0, stream>>>(ctx2, Wp_bf, (float*)d_out);
}